// Round 5
// baseline (421.826 us; speedup 1.0000x reference)
//
#include <hip/hip_runtime.h>
#include <math.h>

#define D_MODEL 1024
#define N_HEADS 16
#define D_HEAD  64
#define SEQ     2048
#define BATCH   2
#define M_TOT   (BATCH*SEQ)   // 4096
#define FFN_DIM 4096

typedef __attribute__((ext_vector_type(8))) short bf16x8;   // 8 bf16 = 4 VGPRs
typedef __attribute__((ext_vector_type(4))) float f32x4;
typedef __attribute__((ext_vector_type(8))) unsigned short u16x8;

__device__ __forceinline__ unsigned short f2bf(float f) {
  unsigned int u = __float_as_uint(f);
  return (unsigned short)((u + 0x7fffu + ((u >> 16) & 1u)) >> 16);  // RNE
}
__device__ __forceinline__ unsigned short f2bf_trunc(float f) {
  return (unsigned short)(__float_as_uint(f) >> 16);   // P in [0,1]: rel err <2^-8
}
__device__ __forceinline__ float bf2f(unsigned short s) {
  return __uint_as_float(((unsigned int)s) << 16);
}

__device__ __forceinline__ float gelu_exact(float x) {
  return 0.5f * x * (1.f + erff(x * 0.70710678118654752f));
}

__device__ __forceinline__ void block_sync() {
  asm volatile("" ::: "memory");
  __builtin_amdgcn_s_barrier();
  asm volatile("" ::: "memory");
}

// async global->LDS, 16B per lane; dest base MUST be wave-uniform (HW adds lane*16)
#define GLL16(g, l) __builtin_amdgcn_global_load_lds( \
    (const __attribute__((address_space(1))) unsigned int*)(g), \
    (__attribute__((address_space(3))) unsigned int*)(l), 16, 0, 0)

// ---------------- fp32 -> bf16 convert, all 4 weight tensors in one launch ------
__global__ __launch_bounds__(256) void cvt_all(const float* __restrict__ qkv_w,
    const float* __restrict__ o_w, const float* __restrict__ w1,
    const float* __restrict__ w2, unsigned short* __restrict__ dst) {
  const long MEGc = 1024*1024;
  long i = (long)(blockIdx.x*256 + threadIdx.x)*4;   // [0, 12M)
  const float* src; long off;
  if (i < 3*MEGc)      { src = qkv_w; off = i; }
  else if (i < 4*MEGc) { src = o_w;  off = i - 3*MEGc; }
  else if (i < 8*MEGc) { src = w1;   off = i - 4*MEGc; }
  else                 { src = w2;   off = i - 8*MEGc; }
  float4 v = *(const float4*)(src + off);
  ushort4 o = { f2bf(v.x), f2bf(v.y), f2bf(v.z), f2bf(v.w) };
  *(ushort4*)(dst + i) = o;
}

// ---------------- LayerNorm: one block (256 thr) per row of 1024, bf16 out ------
__global__ __launch_bounds__(256) void ln_kernel(const float* __restrict__ x,
    const float* __restrict__ w, const float* __restrict__ b,
    unsigned short* __restrict__ out) {
  int row = blockIdx.x;
  const float* xr = x + (size_t)row * D_MODEL;
  int c = threadIdx.x * 4;
  float4 v = *(const float4*)(xr + c);
  float s = v.x + v.y + v.z + v.w;
  __shared__ float red[4];
  #pragma unroll
  for (int o = 32; o > 0; o >>= 1) s += __shfl_down(s, o, 64);
  int wave = threadIdx.x >> 6;
  if ((threadIdx.x & 63) == 0) red[wave] = s;
  __syncthreads();
  float mean = (red[0]+red[1]+red[2]+red[3]) * (1.f/D_MODEL);
  __syncthreads();
  float d0 = v.x-mean, d1 = v.y-mean, d2 = v.z-mean, d3 = v.w-mean;
  float s2 = d0*d0 + d1*d1 + d2*d2 + d3*d3;
  #pragma unroll
  for (int o = 32; o > 0; o >>= 1) s2 += __shfl_down(s2, o, 64);
  if ((threadIdx.x & 63) == 0) red[wave] = s2;
  __syncthreads();
  float var = (red[0]+red[1]+red[2]+red[3]) * (1.f/D_MODEL);
  float rs = rsqrtf(var + 1e-5f);
  float4 wv = *(const float4*)(w + c);
  float4 bv = *(const float4*)(b + c);
  ushort4 o = { f2bf(d0*rs*wv.x + bv.x), f2bf(d1*rs*wv.y + bv.y),
                f2bf(d2*rs*wv.z + bv.z), f2bf(d3*rs*wv.w + bv.w) };
  *(ushort4*)(out + (size_t)row*D_MODEL + c) = o;
}

// ---------------- block swizzle: XCD-chunked + 8-row supertile ------------------
__device__ __forceinline__ void swizzle_block(int nbx, int nby, int& bx, int& by) {
  int nb = nbx * nby;
  int bid = blockIdx.y * nbx + blockIdx.x;
  int chunk = nb >> 3;
  int bid2 = (bid & 7) * chunk + (bid >> 3);   // contiguous region per XCD
  const int GM = 8;
  int ngroup = GM * nbx;
  int g = bid2 / ngroup, rem = bid2 % ngroup;
  by = g*GM + (rem % GM);
  bx = rem / GM;
}

// ---------------- MFMA GEMM, m97-style glld-direct staging ----------------------
// 4-wave (256-thr) blocks, BM=128, BK=32, double-buffered LDS, global_load_lds
// straight to LDS (no VGPR round-trip).  Schedule (race-free, ONE barrier/iter):
//   stage(t+1 -> buf^1) ; compute(buf) ; vmcnt(0) ; barrier
// LDS image byte-identical to the proven reg-staged layout: glld linear dest
// (wave-uniform base + lane*16) + pre-XOR'd global source column.
template<int EPI, bool OBF, int BN>
__global__ __launch_bounds__(256) void gemm_mfma(
    const unsigned short* __restrict__ A, const unsigned short* __restrict__ Bt,
    float* __restrict__ Cf, unsigned short* __restrict__ Cb,
    const float* __restrict__ bias, const float* __restrict__ res,
    int M, int N, int K) {
  constexpr int BM = 128, BK = 32;
  constexpr int TS = (BM + BN) * BK;        // ushorts per staged [A;B] stack
  constexpr int CPT = TS / 2048;            // 16B chunks per thread (4 or 3)
  constexpr int NI = (BN == 128) ? 4 : 2;
  __shared__ unsigned short Ls[2][TS];
  int tid = threadIdx.x;
  int w = tid >> 6, l = tid & 63;
  int lg = l >> 4, lm = l & 15;
  int bx, by;
  swizzle_block(N/BN, M/BM, bx, by);
  int bm = by * BM, bn = bx * BN;
  int wm = (w >> 1) * 64;
  int wn = (w & 1) * (BN/2);

  f32x4 acc[4][NI];
  #pragma unroll
  for (int i = 0; i < 4; ++i)
    #pragma unroll
    for (int j = 0; j < NI; ++j)
      acc[i][j] = (f32x4){0.f, 0.f, 0.f, 0.f};

  // staging map: chunk fc = i*256 + tid; row r = fc>>2 (4 x 8-ushort slots/row);
  // slot (fc&3) holds global k-chunk (fc&3)^swz, swz=(fc>>3)&3 -> source col
  // pre-XOR'd, LDS dest LINEAR at fc*16B (= wave-uniform base + lane*16).
  const unsigned short* gp[CPT];
  #pragma unroll
  for (int i = 0; i < CPT; ++i) {
    int fc = i*256 + tid;
    int r = fc >> 2;
    int swz = (fc >> 3) & 3;
    int col = ((fc & 3) ^ swz) * 8;
    gp[i] = (r < BM) ? (A  + (size_t)(bm + r)*K + col)
                     : (Bt + (size_t)(bn + (r - BM))*K + col);
  }
  int wb = __builtin_amdgcn_readfirstlane(tid & 192);   // w*64, forced SGPR
  auto stage = [&](int buf, int k0) {
    #pragma unroll
    for (int i = 0; i < CPT; ++i)
      GLL16(gp[i] + k0, &Ls[buf][(i*256 + wb)*8]);
  };

  int lgs = lg ^ ((lm >> 1) & 3);
  int aoff = (wm + lm)*BK + lgs*8;
  int boff = BM*BK + (wn + lm)*BK + lgs*8;

  auto compute = [&](const unsigned short* Lp) {
    bf16x8 af[4], bfr[NI];
    #pragma unroll
    for (int i = 0; i < 4; ++i)  af[i]  = *(const bf16x8*)&Lp[aoff + i*512];
    #pragma unroll
    for (int j = 0; j < NI; ++j) bfr[j] = *(const bf16x8*)&Lp[boff + j*512];
    #pragma unroll
    for (int i = 0; i < 4; ++i)
      #pragma unroll
      for (int j = 0; j < NI; ++j)
        acc[i][j] = __builtin_amdgcn_mfma_f32_16x16x32_bf16(af[i], bfr[j], acc[i][j], 0, 0, 0);
  };

  stage(0, 0);
  asm volatile("s_waitcnt vmcnt(0)" ::: "memory");
  block_sync();
  int niter = K / BK;
  for (int kt = 0; kt < niter; ++kt) {
    if (kt + 1 < niter) stage((kt + 1) & 1, (kt + 1)*BK);  // full compute-leg cover
    compute(&Ls[kt & 1][0]);
    if (kt + 1 < niter) {
      asm volatile("s_waitcnt vmcnt(0)" ::: "memory");      // buf^1 resident
      block_sync();                                         // all done reading buf
    }
  }

  // epilogue: C/D layout col = lane&15, row = (lane>>4)*4 + reg
  #pragma unroll
  for (int i = 0; i < 4; ++i) {
    #pragma unroll
    for (int j = 0; j < NI; ++j) {
      int col = bn + wn + j*16 + lm;
      #pragma unroll
      for (int r = 0; r < 4; ++r) {
        int row = bm + wm + i*16 + lg*4 + r;
        float v = acc[i][j][r];
        if (EPI == 1) v = gelu_exact(v + bias[col]);
        if (EPI == 2) v += res[(size_t)row*N + col];
        if (EPI == 3) v += bias[col] + res[(size_t)row*N + col];
        if (OBF) Cb[(size_t)row*N + col] = f2bf(v);
        else     Cf[(size_t)row*N + col] = v;
      }
    }
  }
}

// ---------------- V transpose: qkv V-part -> vT[b][h][d][seq] -------------------
__global__ __launch_bounds__(256) void vtrans_kernel(
    const unsigned short* __restrict__ qkvb, unsigned short* __restrict__ vT) {
  __shared__ unsigned short T[64*72];
  int nt = blockIdx.x, h = blockIdx.y, b = blockIdx.z;
  int tid = threadIdx.x;
  const unsigned short* vb = qkvb + (size_t)(b*SEQ)*(3*D_MODEL) + 2*D_MODEL + h*D_HEAD;
  #pragma unroll
  for (int it = 0; it < 2; ++it) {
    int idx = tid + it*256;
    int r = idx >> 3, c8 = (idx & 7)*8;
    *(u16x8*)&T[r*72 + c8] = *(const u16x8*)(vb + (size_t)(nt*64 + r)*(3*D_MODEL) + c8);
  }
  __syncthreads();
  unsigned short* vto = vT + ((size_t)(b*N_HEADS + h)*D_HEAD)*SEQ + nt*64;
  #pragma unroll
  for (int it = 0; it < 2; ++it) {
    int idx = tid + it*256;
    int d = idx >> 3, s8 = (idx & 7)*8;
    u16x8 o;
    #pragma unroll
    for (int i = 0; i < 8; ++i) o[i] = T[(s8+i)*72 + d];
    *(u16x8*)(vto + (size_t)d*SEQ + s8) = o;
  }
}

// ---------------- MFMA flash attention: single 64-row q-tile per block ---------
// Round-5 restructure: one q-tile per block (grid 32x16x2 = 1024 blocks, 4 waves)
// instead of paired tiles in 512 blocks.  Per-block LDS ~26.9KB -> 5-6 resident
// blocks/CU (was 2), i.e. 20-24 waves/CU of independent flash loops: softmax
// VALU chains + LDS round-trips of one block now overlap other blocks' MFMA.
// Heaviest blocks (qt=31) launch first: qt = 31 - blockIdx.x.
// Pw pad 72->68: P-scatter write banks spread over all 32 (was 4 lanes on each
// of banks 0-7 -> part of the 3.75M SQ_LDS_BANK_CONFLICT).
#define ATT_PAD 72
#define PW_PAD  68
__device__ __forceinline__ void attn_step(
    const bf16x8* aq, float* m_i, float* l_i, f32x4* acc_o,
    const unsigned short* __restrict__ Ks, const unsigned short* __restrict__ Vt,
    unsigned short* __restrict__ pw, int lg, int lm, int qoff, bool diag) {
  f32x4 sacc[4];
  #pragma unroll
  for (int j = 0; j < 4; ++j) sacc[j] = (f32x4){0.f, 0.f, 0.f, 0.f};
  #pragma unroll
  for (int s = 0; s < 2; ++s)
    #pragma unroll
    for (int j = 0; j < 4; ++j)
      sacc[j] = __builtin_amdgcn_mfma_f32_16x16x32_bf16(
          aq[s], *(const bf16x8*)&Ks[(j*16+lm)*ATT_PAD + s*32 + lg*8], sacc[j], 0, 0, 0);
  if (diag) {
    #pragma unroll
    for (int j = 0; j < 4; ++j)
      #pragma unroll
      for (int r = 0; r < 4; ++r)
        if (j*16 + lm > qoff + lg*4 + r) sacc[j][r] = -INFINITY;
  }
  float alpha[4];
  #pragma unroll
  for (int r = 0; r < 4; ++r) {
    float rm = fmaxf(fmaxf(sacc[0][r], sacc[1][r]), fmaxf(sacc[2][r], sacc[3][r]));
    #pragma unroll
    for (int o = 1; o < 16; o <<= 1) rm = fmaxf(rm, __shfl_xor(rm, o));
    float mn = fmaxf(m_i[r], rm);
    alpha[r] = __expf(m_i[r] - mn);
    float rsum = 0.f;
    #pragma unroll
    for (int j = 0; j < 4; ++j) {
      float p = __expf(sacc[j][r] - mn);
      sacc[j][r] = p; rsum += p;
    }
    #pragma unroll
    for (int o = 1; o < 16; o <<= 1) rsum += __shfl_xor(rsum, o);
    l_i[r] = l_i[r]*alpha[r] + rsum;
    m_i[r] = mn;
  }
  #pragma unroll
  for (int j = 0; j < 4; ++j)
    #pragma unroll
    for (int r = 0; r < 4; ++r)
      pw[(lg*4 + r)*PW_PAD + j*16 + lm] = f2bf_trunc(sacc[j][r]);
  #pragma unroll
  for (int j = 0; j < 4; ++j)
    #pragma unroll
    for (int r = 0; r < 4; ++r)
      acc_o[j][r] *= alpha[r];
  #pragma unroll
  for (int s = 0; s < 2; ++s) {
    bf16x8 ap = *(const bf16x8*)&pw[lm*PW_PAD + s*32 + lg*8];
    #pragma unroll
    for (int j = 0; j < 4; ++j)
      acc_o[j] = __builtin_amdgcn_mfma_f32_16x16x32_bf16(
          ap, *(const bf16x8*)&Vt[(j*16+lm)*ATT_PAD + s*32 + lg*8], acc_o[j], 0, 0, 0);
  }
}

__global__ __launch_bounds__(256) void attn_mfma_kernel(
    const unsigned short* __restrict__ qkvb, const unsigned short* __restrict__ vT,
    unsigned short* __restrict__ out) {
  __shared__ unsigned short Ks[64*ATT_PAD];
  __shared__ unsigned short Vt[64*ATT_PAD];
  __shared__ unsigned short Pw[4][16*PW_PAD];

  int qt = 31 - blockIdx.x;          // heaviest first
  int h = blockIdx.y, b = blockIdx.z;
  int tid = threadIdx.x;
  int w = tid >> 6, l = tid & 63;
  int lg = l >> 4, lm = l & 15;

  const size_t rs3 = 3*D_MODEL;
  const unsigned short* qb  = qkvb + (size_t)(b*SEQ)*rs3 + h*D_HEAD;
  const unsigned short* kb  = qb + D_MODEL;
  const unsigned short* vtb = vT + ((size_t)(b*N_HEADS + h)*D_HEAD)*SEQ;

  bf16x8 aq[2];
  int qr = qt*64 + w*16 + lm;
  #pragma unroll
  for (int s = 0; s < 2; ++s) {
    u16x8 t = *(const u16x8*)(qb + (size_t)qr*rs3 + s*32 + lg*8);
    bf16x8 rq;
    #pragma unroll
    for (int i = 0; i < 8; ++i) rq[i] = (short)f2bf(bf2f(t[i]) * 0.125f);
    aq[s] = rq;
  }

  float m_i[4], l_i[4];
  f32x4 o_a[4];
  #pragma unroll
  for (int r = 0; r < 4; ++r) { m_i[r] = -INFINITY; l_i[r] = 0.f; }
  #pragma unroll
  for (int j = 0; j < 4; ++j) o_a[j] = (f32x4){0.f,0.f,0.f,0.f};

  unsigned short* pw = &Pw[w][0];

  int sidx0 = tid, sidx1 = tid + 256;
  int sr0 = sidx0 >> 3, sc0 = (sidx0 & 7)*8;
  int sr1 = sidx1 >> 3, sc1 = (sidx1 & 7)*8;

  u16x8 kreg[2], vreg[2];
  auto prefetch = [&](int kt) {
    kreg[0] = *(const u16x8*)(kb  + (size_t)(kt*64 + sr0)*rs3 + sc0);
    kreg[1] = *(const u16x8*)(kb  + (size_t)(kt*64 + sr1)*rs3 + sc1);
    vreg[0] = *(const u16x8*)(vtb + (size_t)sr0*SEQ + kt*64 + sc0);
    vreg[1] = *(const u16x8*)(vtb + (size_t)sr1*SEQ + kt*64 + sc1);
  };

  prefetch(0);
  for (int kt = 0; kt <= qt; ++kt) {
    __syncthreads();
    *(u16x8*)&Ks[sr0*ATT_PAD + sc0] = kreg[0];
    *(u16x8*)&Ks[sr1*ATT_PAD + sc1] = kreg[1];
    *(u16x8*)&Vt[sr0*ATT_PAD + sc0] = vreg[0];
    *(u16x8*)&Vt[sr1*ATT_PAD + sc1] = vreg[1];
    __syncthreads();
    if (kt < qt) prefetch(kt+1);
    attn_step(aq, m_i, l_i, o_a, Ks, Vt, pw, lg, lm, w*16, kt == qt);
  }

  #pragma unroll
  for (int r = 0; r < 4; ++r) {
    float inv = 1.f / l_i[r];
    int q = qt*64 + w*16 + lg*4 + r;
    #pragma unroll
    for (int j = 0; j < 4; ++j)
      out[((size_t)(b*SEQ + q))*D_MODEL + h*D_HEAD + j*16 + lm] = f2bf(o_a[j][r]*inv);
  }
}

extern "C" void kernel_launch(void* const* d_in, const int* in_sizes, int n_in,
                              void* d_out, int out_size, void* d_ws, size_t ws_size,
                              hipStream_t stream) {
  const float* x      = (const float*)d_in[0];
  const float* ln1_w  = (const float*)d_in[1];
  const float* ln1_b  = (const float*)d_in[2];
  const float* ln2_w  = (const float*)d_in[3];
  const float* ln2_b  = (const float*)d_in[4];
  const float* qkv_w  = (const float*)d_in[5];
  const float* o_w    = (const float*)d_in[6];
  const float* ffn_w1 = (const float*)d_in[7];
  const float* ffn_b1 = (const float*)d_in[8];
  const float* ffn_w2 = (const float*)d_in[9];
  const float* ffn_b2 = (const float*)d_in[10];
  float* out = (float*)d_out;
  float* ws  = (float*)d_ws;

  const size_t MEG = 1024*1024;
  unsigned short* wqkv = (unsigned short*)ws;              // 3M shorts
  unsigned short* wo   = wqkv + 3*MEG;                     // 1M
  unsigned short* w1   = wo   + 1*MEG;                     // 4M
  unsigned short* w2   = w1   + 4*MEG;                     // 4M
  unsigned short* hbf    = (unsigned short*)(ws + 6*MEG);  // [6M,8M)  h / h2
  unsigned short* attnbf = (unsigned short*)(ws + 8*MEG);  // [8M,10M)
  float* x1  = ws + 10*MEG;                                // [10M,14M)
  unsigned short* qkvb = (unsigned short*)(ws + 14*MEG);   // [14M,20M) dead after attn
  unsigned short* ffbf = (unsigned short*)(ws + 14*MEG);   // [14M,22M) reuses qkvb
  unsigned short* vT   = (unsigned short*)(ws + 22*MEG);   // [22M,24M)

  // 0. weights -> bf16 (single launch)
  cvt_all<<<12*MEG/1024, 256, 0, stream>>>(qkv_w, o_w, ffn_w1, ffn_w2, wqkv);
  // 1. h = LN1(x) -> bf16
  ln_kernel<<<M_TOT, 256, 0, stream>>>(x, ln1_w, ln1_b, hbf);
  // 2. qkv = h @ qkv_w.T  (4096 x 3072 x 1024) -> bf16, 128x128 glld tiles
  gemm_mfma<0,true,128><<<dim3(3*D_MODEL/128, M_TOT/128), 256, 0, stream>>>(
      hbf, wqkv, nullptr, qkvb, nullptr, nullptr, M_TOT, 3*D_MODEL, D_MODEL);
  // 2.5 vT = transpose(V)
  vtrans_kernel<<<dim3(SEQ/64, N_HEADS, BATCH), 256, 0, stream>>>(qkvb, vT);
  // 3. attn = causal MHA -> bf16, single-tile flash, 1024 blocks
  attn_mfma_kernel<<<dim3(32, N_HEADS, BATCH), 256, 0, stream>>>(qkvb, vT, attnbf);
  // 4. x1 = x + attn @ o_w.T  (4096 x 1024 x 1024) -> fp32, 128x64 glld tiles
  gemm_mfma<2,false,64><<<dim3(D_MODEL/64, M_TOT/128), 256, 0, stream>>>(
      attnbf, wo, x1, nullptr, nullptr, x, M_TOT, D_MODEL, D_MODEL);
  // 5. h2 = LN2(x1) -> bf16
  ln_kernel<<<M_TOT, 256, 0, stream>>>(x1, ln2_w, ln2_b, hbf);
  // 6. ff = gelu(h2 @ ffn_w1.T + b1)  (4096 x 4096 x 1024) -> bf16, 128x128 glld
  gemm_mfma<1,true,128><<<dim3(FFN_DIM/128, M_TOT/128), 256, 0, stream>>>(
      hbf, w1, nullptr, ffbf, ffn_b1, nullptr, M_TOT, FFN_DIM, D_MODEL);
  // 7. out = x1 + ff @ ffn_w2.T + b2  (4096 x 1024 x 4096) -> fp32, 128x64 glld
  gemm_mfma<3,false,64><<<dim3(D_MODEL/64, M_TOT/128), 256, 0, stream>>>(
      ffbf, w2, out, nullptr, ffn_b2, x1, M_TOT, D_MODEL, FFN_DIM);
}

// Round 6
// 373.172 us; speedup vs baseline: 1.1304x; 1.1304x over previous
//
#include <hip/hip_runtime.h>
#include <math.h>

#define D_MODEL 1024
#define N_HEADS 16
#define D_HEAD  64
#define SEQ     2048
#define BATCH   2
#define M_TOT   (BATCH*SEQ)   // 4096
#define FFN_DIM 4096

typedef __attribute__((ext_vector_type(8))) short bf16x8;   // 8 bf16 = 4 VGPRs
typedef __attribute__((ext_vector_type(4))) float f32x4;
typedef __attribute__((ext_vector_type(8))) unsigned short u16x8;

__device__ __forceinline__ unsigned short f2bf(float f) {
  unsigned int u = __float_as_uint(f);
  return (unsigned short)((u + 0x7fffu + ((u >> 16) & 1u)) >> 16);  // RNE
}
__device__ __forceinline__ unsigned short f2bf_trunc(float f) {
  return (unsigned short)(__float_as_uint(f) >> 16);   // P in [0,1]: rel err <2^-8
}
__device__ __forceinline__ float bf2f(unsigned short s) {
  return __uint_as_float(((unsigned int)s) << 16);
}

__device__ __forceinline__ float gelu_exact(float x) {
  return 0.5f * x * (1.f + erff(x * 0.70710678118654752f));
}

__device__ __forceinline__ void block_sync() {
  asm volatile("" ::: "memory");
  __builtin_amdgcn_s_barrier();
  asm volatile("" ::: "memory");
}

template<int N> __device__ __forceinline__ void waitcnt_vm() {
  if constexpr (N == 0) asm volatile("s_waitcnt vmcnt(0)" ::: "memory");
  else if constexpr (N == 3) asm volatile("s_waitcnt vmcnt(3)" ::: "memory");
  else if constexpr (N == 4) asm volatile("s_waitcnt vmcnt(4)" ::: "memory");
  else static_assert(N == 0 || N == 3 || N == 4, "unsupported vmcnt");
}

// async global->LDS, 16B per lane; dest base MUST be wave-uniform (HW adds lane*16)
#define GLL16(g, l) __builtin_amdgcn_global_load_lds( \
    (const __attribute__((address_space(1))) unsigned int*)(g), \
    (__attribute__((address_space(3))) unsigned int*)(l), 16, 0, 0)

// ---------------- fp32 -> bf16 convert, all 4 weight tensors in one launch ------
__global__ __launch_bounds__(256) void cvt_all(const float* __restrict__ qkv_w,
    const float* __restrict__ o_w, const float* __restrict__ w1,
    const float* __restrict__ w2, unsigned short* __restrict__ dst) {
  const long MEGc = 1024*1024;
  long i = (long)(blockIdx.x*256 + threadIdx.x)*4;   // [0, 12M)
  const float* src; long off;
  if (i < 3*MEGc)      { src = qkv_w; off = i; }
  else if (i < 4*MEGc) { src = o_w;  off = i - 3*MEGc; }
  else if (i < 8*MEGc) { src = w1;   off = i - 4*MEGc; }
  else                 { src = w2;   off = i - 8*MEGc; }
  float4 v = *(const float4*)(src + off);
  ushort4 o = { f2bf(v.x), f2bf(v.y), f2bf(v.z), f2bf(v.w) };
  *(ushort4*)(dst + i) = o;
}

// ---------------- LayerNorm: one block (256 thr) per row of 1024, bf16 out ------
__global__ __launch_bounds__(256) void ln_kernel(const float* __restrict__ x,
    const float* __restrict__ w, const float* __restrict__ b,
    unsigned short* __restrict__ out) {
  int row = blockIdx.x;
  const float* xr = x + (size_t)row * D_MODEL;
  int c = threadIdx.x * 4;
  float4 v = *(const float4*)(xr + c);
  float s = v.x + v.y + v.z + v.w;
  __shared__ float red[4];
  #pragma unroll
  for (int o = 32; o > 0; o >>= 1) s += __shfl_down(s, o, 64);
  int wave = threadIdx.x >> 6;
  if ((threadIdx.x & 63) == 0) red[wave] = s;
  __syncthreads();
  float mean = (red[0]+red[1]+red[2]+red[3]) * (1.f/D_MODEL);
  __syncthreads();
  float d0 = v.x-mean, d1 = v.y-mean, d2 = v.z-mean, d3 = v.w-mean;
  float s2 = d0*d0 + d1*d1 + d2*d2 + d3*d3;
  #pragma unroll
  for (int o = 32; o > 0; o >>= 1) s2 += __shfl_down(s2, o, 64);
  if ((threadIdx.x & 63) == 0) red[wave] = s2;
  __syncthreads();
  float var = (red[0]+red[1]+red[2]+red[3]) * (1.f/D_MODEL);
  float rs = rsqrtf(var + 1e-5f);
  float4 wv = *(const float4*)(w + c);
  float4 bv = *(const float4*)(b + c);
  ushort4 o = { f2bf(d0*rs*wv.x + bv.x), f2bf(d1*rs*wv.y + bv.y),
                f2bf(d2*rs*wv.z + bv.z), f2bf(d3*rs*wv.w + bv.w) };
  *(ushort4*)(out + (size_t)row*D_MODEL + c) = o;
}

// ---------------- block swizzle: XCD-chunked + 8-row supertile ------------------
__device__ __forceinline__ void swizzle_block(int nbx, int nby, int& bx, int& by) {
  int nb = nbx * nby;
  int bid = blockIdx.y * nbx + blockIdx.x;
  int chunk = nb >> 3;
  int bid2 = (bid & 7) * chunk + (bid >> 3);   // contiguous region per XCD
  const int GM = 8;
  int ngroup = GM * nbx;
  int g = bid2 / ngroup, rem = bid2 % ngroup;
  by = g*GM + (rem % GM);
  bx = rem / GM;
}

// ---------------- MFMA GEMM, glld-direct, depth-2 counted-vmcnt pipeline --------
// 4-wave (256-thr) blocks, BM=128, BK=32, TRIPLE-buffered LDS.  Per iteration:
//   stage(t+2 -> buf[(b0+2)%3]) ; compute(buf[b0]) ; vmcnt(CPT) ; barrier
// vmcnt(CPT) (3 or 4, NEVER 0 in steady state) waits only on stage(t+1), which
// was issued a full iteration earlier -> HBM latency covered by a whole
// compute+barrier leg.  stage(t+2) targets the buffer read at iter t-1, whose
// reads all completed before barrier(t-1->t).  LDS image: glld linear dest
// (wave-uniform base + lane*16) + pre-XOR'd global source column -> swizzled
// layout, conflict-free ds_read_b128 fragments.
template<int EPI, bool OBF, int BN>
__global__ __launch_bounds__(256) void gemm_mfma(
    const unsigned short* __restrict__ A, const unsigned short* __restrict__ Bt,
    float* __restrict__ Cf, unsigned short* __restrict__ Cb,
    const float* __restrict__ bias, const float* __restrict__ res,
    int M, int N, int K) {
  constexpr int BM = 128, BK = 32;
  constexpr int TS = (BM + BN) * BK;        // ushorts per staged [A;B] stack
  constexpr int CPT = TS / 2048;            // 16B chunks per thread (4 or 3)
  constexpr int NI = (BN == 128) ? 4 : 2;
  __shared__ unsigned short Ls[3][TS];
  int tid = threadIdx.x;
  int w = tid >> 6, l = tid & 63;
  int lg = l >> 4, lm = l & 15;
  int bx, by;
  swizzle_block(N/BN, M/BM, bx, by);
  int bm = by * BM, bn = bx * BN;
  int wm = (w >> 1) * 64;
  int wn = (w & 1) * (BN/2);

  f32x4 acc[4][NI];
  #pragma unroll
  for (int i = 0; i < 4; ++i)
    #pragma unroll
    for (int j = 0; j < NI; ++j)
      acc[i][j] = (f32x4){0.f, 0.f, 0.f, 0.f};

  // staging map: chunk fc = i*256 + tid; row r = fc>>2 (4 x 8-ushort slots/row);
  // slot (fc&3) holds global k-chunk (fc&3)^swz, swz=(fc>>3)&3 -> source col
  // pre-XOR'd, LDS dest LINEAR at fc*16B (= wave-uniform base + lane*16).
  const unsigned short* gp[CPT];
  #pragma unroll
  for (int i = 0; i < CPT; ++i) {
    int fc = i*256 + tid;
    int r = fc >> 2;
    int swz = (fc >> 3) & 3;
    int col = ((fc & 3) ^ swz) * 8;
    gp[i] = (r < BM) ? (A  + (size_t)(bm + r)*K + col)
                     : (Bt + (size_t)(bn + (r - BM))*K + col);
  }
  int wb = __builtin_amdgcn_readfirstlane(tid & 192);   // w*64, forced SGPR
  auto stage = [&](int buf, int k0) {
    #pragma unroll
    for (int i = 0; i < CPT; ++i)
      GLL16(gp[i] + k0, &Ls[buf][(i*256 + wb)*8]);
  };

  int lgs = lg ^ ((lm >> 1) & 3);
  int aoff = (wm + lm)*BK + lgs*8;
  int boff = BM*BK + (wn + lm)*BK + lgs*8;

  auto compute = [&](const unsigned short* Lp) {
    bf16x8 af[4], bfr[NI];
    #pragma unroll
    for (int i = 0; i < 4; ++i)  af[i]  = *(const bf16x8*)&Lp[aoff + i*512];
    #pragma unroll
    for (int j = 0; j < NI; ++j) bfr[j] = *(const bf16x8*)&Lp[boff + j*512];
    #pragma unroll
    for (int i = 0; i < 4; ++i)
      #pragma unroll
      for (int j = 0; j < NI; ++j)
        acc[i][j] = __builtin_amdgcn_mfma_f32_16x16x32_bf16(af[i], bfr[j], acc[i][j], 0, 0, 0);
  };

  stage(0, 0);
  stage(1, BK);
  waitcnt_vm<CPT>();          // tile 0 resident, tile 1 in flight
  block_sync();
  int niter = K / BK;
  int b0 = 0;
  for (int kt = 0; kt < niter; ++kt) {
    int b2 = (b0 + 2 >= 3) ? b0 - 1 : b0 + 2;
    if (kt + 2 < niter) stage(b2, (kt + 2)*BK);   // buffer read at iter kt-1
    compute(&Ls[b0][0]);
    if (kt + 1 < niter) {
      if (kt + 2 < niter) waitcnt_vm<CPT>();      // tile kt+1 resident, kt+2 in flight
      else                waitcnt_vm<0>();        // tail drain (once)
      block_sync();
    }
    b0 = (b0 + 1 >= 3) ? 0 : b0 + 1;
  }

  // epilogue: C/D layout col = lane&15, row = (lane>>4)*4 + reg
  #pragma unroll
  for (int i = 0; i < 4; ++i) {
    #pragma unroll
    for (int j = 0; j < NI; ++j) {
      int col = bn + wn + j*16 + lm;
      #pragma unroll
      for (int r = 0; r < 4; ++r) {
        int row = bm + wm + i*16 + lg*4 + r;
        float v = acc[i][j][r];
        if (EPI == 1) v = gelu_exact(v + bias[col]);
        if (EPI == 2) v += res[(size_t)row*N + col];
        if (EPI == 3) v += bias[col] + res[(size_t)row*N + col];
        if (OBF) Cb[(size_t)row*N + col] = f2bf(v);
        else     Cf[(size_t)row*N + col] = v;
      }
    }
  }
}

// ---------------- V transpose: qkv V-part -> vT[b][h][d][seq] -------------------
__global__ __launch_bounds__(256) void vtrans_kernel(
    const unsigned short* __restrict__ qkvb, unsigned short* __restrict__ vT) {
  __shared__ unsigned short T[64*72];
  int nt = blockIdx.x, h = blockIdx.y, b = blockIdx.z;
  int tid = threadIdx.x;
  const unsigned short* vb = qkvb + (size_t)(b*SEQ)*(3*D_MODEL) + 2*D_MODEL + h*D_HEAD;
  #pragma unroll
  for (int it = 0; it < 2; ++it) {
    int idx = tid + it*256;
    int r = idx >> 3, c8 = (idx & 7)*8;
    *(u16x8*)&T[r*72 + c8] = *(const u16x8*)(vb + (size_t)(nt*64 + r)*(3*D_MODEL) + c8);
  }
  __syncthreads();
  unsigned short* vto = vT + ((size_t)(b*N_HEADS + h)*D_HEAD)*SEQ + nt*64;
  #pragma unroll
  for (int it = 0; it < 2; ++it) {
    int idx = tid + it*256;
    int d = idx >> 3, s8 = (idx & 7)*8;
    u16x8 o;
    #pragma unroll
    for (int i = 0; i < 8; ++i) o[i] = T[(s8+i)*72 + d];
    *(u16x8*)(vto + (size_t)d*SEQ + s8) = o;
  }
}

// ---------------- MFMA flash attention: paired q-tiles (r4 structure) + ---------
// ---------------- double-buffered K/V LDS: ONE barrier per KV step --------------
// r5 lesson: un-pairing doubled per-score sync/staging overhead (76->143us).
// Here pairing is kept (2 attn_steps per staged tile) and the second barrier is
// removed via K/V double-buffer: prefetch(t+1) -> barrier -> ds_write(t+1 ->
// buf^1) -> compute(buf).  The write targets the buffer last read at t-1 (all
// reads done before this barrier), and writes overlap compute on the other
// buffer.  Pw pad 68 (write-conflict-free scatter).
#define ATT_PAD 72
#define PW_PAD  68
__device__ __forceinline__ void attn_step(
    const bf16x8* aq, float* m_i, float* l_i, f32x4* acc_o,
    const unsigned short* __restrict__ Ks, const unsigned short* __restrict__ Vt,
    unsigned short* __restrict__ pw, int lg, int lm, int qoff, bool diag) {
  f32x4 sacc[4];
  #pragma unroll
  for (int j = 0; j < 4; ++j) sacc[j] = (f32x4){0.f, 0.f, 0.f, 0.f};
  #pragma unroll
  for (int s = 0; s < 2; ++s)
    #pragma unroll
    for (int j = 0; j < 4; ++j)
      sacc[j] = __builtin_amdgcn_mfma_f32_16x16x32_bf16(
          aq[s], *(const bf16x8*)&Ks[(j*16+lm)*ATT_PAD + s*32 + lg*8], sacc[j], 0, 0, 0);
  if (diag) {
    #pragma unroll
    for (int j = 0; j < 4; ++j)
      #pragma unroll
      for (int r = 0; r < 4; ++r)
        if (j*16 + lm > qoff + lg*4 + r) sacc[j][r] = -INFINITY;
  }
  float alpha[4];
  #pragma unroll
  for (int r = 0; r < 4; ++r) {
    float rm = fmaxf(fmaxf(sacc[0][r], sacc[1][r]), fmaxf(sacc[2][r], sacc[3][r]));
    #pragma unroll
    for (int o = 1; o < 16; o <<= 1) rm = fmaxf(rm, __shfl_xor(rm, o));
    float mn = fmaxf(m_i[r], rm);
    alpha[r] = __expf(m_i[r] - mn);
    float rsum = 0.f;
    #pragma unroll
    for (int j = 0; j < 4; ++j) {
      float p = __expf(sacc[j][r] - mn);
      sacc[j][r] = p; rsum += p;
    }
    #pragma unroll
    for (int o = 1; o < 16; o <<= 1) rsum += __shfl_xor(rsum, o);
    l_i[r] = l_i[r]*alpha[r] + rsum;
    m_i[r] = mn;
  }
  #pragma unroll
  for (int j = 0; j < 4; ++j)
    #pragma unroll
    for (int r = 0; r < 4; ++r)
      pw[(lg*4 + r)*PW_PAD + j*16 + lm] = f2bf_trunc(sacc[j][r]);
  #pragma unroll
  for (int j = 0; j < 4; ++j)
    #pragma unroll
    for (int r = 0; r < 4; ++r)
      acc_o[j][r] *= alpha[r];
  #pragma unroll
  for (int s = 0; s < 2; ++s) {
    bf16x8 ap = *(const bf16x8*)&pw[lm*PW_PAD + s*32 + lg*8];
    #pragma unroll
    for (int j = 0; j < 4; ++j)
      acc_o[j] = __builtin_amdgcn_mfma_f32_16x16x32_bf16(
          ap, *(const bf16x8*)&Vt[(j*16+lm)*ATT_PAD + s*32 + lg*8], acc_o[j], 0, 0, 0);
  }
}

__global__ __launch_bounds__(256) void attn_mfma_kernel(
    const unsigned short* __restrict__ qkvb, const unsigned short* __restrict__ vT,
    unsigned short* __restrict__ out) {
  __shared__ unsigned short Ks[2][64*ATT_PAD];
  __shared__ unsigned short Vt[2][64*ATT_PAD];
  __shared__ unsigned short Pw[4][16*PW_PAD];

  int pr = blockIdx.x, h = blockIdx.y, b = blockIdx.z;
  int qtH = 31 - pr, qtL = pr;
  int tid = threadIdx.x;
  int w = tid >> 6, l = tid & 63;
  int lg = l >> 4, lm = l & 15;

  const size_t rs3 = 3*D_MODEL;
  const unsigned short* qb  = qkvb + (size_t)(b*SEQ)*rs3 + h*D_HEAD;
  const unsigned short* kb  = qb + D_MODEL;
  const unsigned short* vtb = vT + ((size_t)(b*N_HEADS + h)*D_HEAD)*SEQ;

  bf16x8 aqH[2], aqL[2];
  int qrH = qtH*64 + w*16 + lm, qrL = qtL*64 + w*16 + lm;
  #pragma unroll
  for (int s = 0; s < 2; ++s) {
    u16x8 tH = *(const u16x8*)(qb + (size_t)qrH*rs3 + s*32 + lg*8);
    u16x8 tL = *(const u16x8*)(qb + (size_t)qrL*rs3 + s*32 + lg*8);
    bf16x8 rH, rL;
    #pragma unroll
    for (int i = 0; i < 8; ++i) {
      rH[i] = (short)f2bf(bf2f(tH[i]) * 0.125f);
      rL[i] = (short)f2bf(bf2f(tL[i]) * 0.125f);
    }
    aqH[s] = rH; aqL[s] = rL;
  }

  float mH[4], lH[4], mL[4], lL[4];
  f32x4 oH[4], oL[4];
  #pragma unroll
  for (int r = 0; r < 4; ++r) { mH[r] = -INFINITY; lH[r] = 0.f; mL[r] = -INFINITY; lL[r] = 0.f; }
  #pragma unroll
  for (int j = 0; j < 4; ++j) { oH[j] = (f32x4){0.f,0.f,0.f,0.f}; oL[j] = (f32x4){0.f,0.f,0.f,0.f}; }

  unsigned short* pw = &Pw[w][0];

  int sidx0 = tid, sidx1 = tid + 256;
  int sr0 = sidx0 >> 3, sc0 = (sidx0 & 7)*8;
  int sr1 = sidx1 >> 3, sc1 = (sidx1 & 7)*8;

  u16x8 kreg[2], vreg[2];
  auto prefetch = [&](int kt) {
    kreg[0] = *(const u16x8*)(kb  + (size_t)(kt*64 + sr0)*rs3 + sc0);
    kreg[1] = *(const u16x8*)(kb  + (size_t)(kt*64 + sr1)*rs3 + sc1);
    vreg[0] = *(const u16x8*)(vtb + (size_t)sr0*SEQ + kt*64 + sc0);
    vreg[1] = *(const u16x8*)(vtb + (size_t)sr1*SEQ + kt*64 + sc1);
  };
  auto dswrite = [&](int buf) {
    *(u16x8*)&Ks[buf][sr0*ATT_PAD + sc0] = kreg[0];
    *(u16x8*)&Ks[buf][sr1*ATT_PAD + sc1] = kreg[1];
    *(u16x8*)&Vt[buf][sr0*ATT_PAD + sc0] = vreg[0];
    *(u16x8*)&Vt[buf][sr1*ATT_PAD + sc1] = vreg[1];
  };

  prefetch(0);
  dswrite(0);                         // buffer 0, no readers yet
  for (int kt = 0; kt <= qtH; ++kt) {
    int cb = kt & 1;
    if (kt < qtH) prefetch(kt+1);
    __syncthreads();                  // writes of tile kt visible; reads of buf^1 done
    if (kt < qtH) dswrite(cb ^ 1);    // overlaps compute below (other buffer)
    attn_step(aqH, mH, lH, oH, &Ks[cb][0], &Vt[cb][0], pw, lg, lm, w*16, kt == qtH);
    if (kt <= qtL)
      attn_step(aqL, mL, lL, oL, &Ks[cb][0], &Vt[cb][0], pw, lg, lm, w*16, kt == qtL);
  }

  #pragma unroll
  for (int r = 0; r < 4; ++r) {
    float invH = 1.f / lH[r], invL = 1.f / lL[r];
    int qH = qtH*64 + w*16 + lg*4 + r;
    int qL = qtL*64 + w*16 + lg*4 + r;
    #pragma unroll
    for (int j = 0; j < 4; ++j) {
      out[((size_t)(b*SEQ + qH))*D_MODEL + h*D_HEAD + j*16 + lm] = f2bf(oH[j][r]*invH);
      out[((size_t)(b*SEQ + qL))*D_MODEL + h*D_HEAD + j*16 + lm] = f2bf(oL[j][r]*invL);
    }
  }
}

extern "C" void kernel_launch(void* const* d_in, const int* in_sizes, int n_in,
                              void* d_out, int out_size, void* d_ws, size_t ws_size,
                              hipStream_t stream) {
  const float* x      = (const float*)d_in[0];
  const float* ln1_w  = (const float*)d_in[1];
  const float* ln1_b  = (const float*)d_in[2];
  const float* ln2_w  = (const float*)d_in[3];
  const float* ln2_b  = (const float*)d_in[4];
  const float* qkv_w  = (const float*)d_in[5];
  const float* o_w    = (const float*)d_in[6];
  const float* ffn_w1 = (const float*)d_in[7];
  const float* ffn_b1 = (const float*)d_in[8];
  const float* ffn_w2 = (const float*)d_in[9];
  const float* ffn_b2 = (const float*)d_in[10];
  float* out = (float*)d_out;
  float* ws  = (float*)d_ws;

  const size_t MEG = 1024*1024;
  unsigned short* wqkv = (unsigned short*)ws;              // 3M shorts
  unsigned short* wo   = wqkv + 3*MEG;                     // 1M
  unsigned short* w1   = wo   + 1*MEG;                     // 4M
  unsigned short* w2   = w1   + 4*MEG;                     // 4M
  unsigned short* hbf    = (unsigned short*)(ws + 6*MEG);  // [6M,8M)  h / h2
  unsigned short* attnbf = (unsigned short*)(ws + 8*MEG);  // [8M,10M)
  float* x1  = ws + 10*MEG;                                // [10M,14M)
  unsigned short* qkvb = (unsigned short*)(ws + 14*MEG);   // [14M,20M) dead after attn
  unsigned short* ffbf = (unsigned short*)(ws + 14*MEG);   // [14M,22M) reuses qkvb
  unsigned short* vT   = (unsigned short*)(ws + 22*MEG);   // [22M,24M)

  // 0. weights -> bf16 (single launch)
  cvt_all<<<12*MEG/1024, 256, 0, stream>>>(qkv_w, o_w, ffn_w1, ffn_w2, wqkv);
  // 1. h = LN1(x) -> bf16
  ln_kernel<<<M_TOT, 256, 0, stream>>>(x, ln1_w, ln1_b, hbf);
  // 2. qkv = h @ qkv_w.T  (4096 x 3072 x 1024) -> bf16, 128x128 depth-2 pipeline
  gemm_mfma<0,true,128><<<dim3(3*D_MODEL/128, M_TOT/128), 256, 0, stream>>>(
      hbf, wqkv, nullptr, qkvb, nullptr, nullptr, M_TOT, 3*D_MODEL, D_MODEL);
  // 2.5 vT = transpose(V)
  vtrans_kernel<<<dim3(SEQ/64, N_HEADS, BATCH), 256, 0, stream>>>(qkvb, vT);
  // 3. attn = causal MHA -> bf16, paired flash + K/V double-buffer (1 barrier/step)
  attn_mfma_kernel<<<dim3(16, N_HEADS, BATCH), 256, 0, stream>>>(qkvb, vT, attnbf);
  // 4. x1 = x + attn @ o_w.T  (4096 x 1024 x 1024) -> fp32, 128x64 depth-2
  gemm_mfma<2,false,64><<<dim3(D_MODEL/64, M_TOT/128), 256, 0, stream>>>(
      attnbf, wo, x1, nullptr, nullptr, x, M_TOT, D_MODEL, D_MODEL);
  // 5. h2 = LN2(x1) -> bf16
  ln_kernel<<<M_TOT, 256, 0, stream>>>(x1, ln2_w, ln2_b, hbf);
  // 6. ff = gelu(h2 @ ffn_w1.T + b1)  (4096 x 4096 x 1024) -> bf16, 128x128 depth-2
  gemm_mfma<1,true,128><<<dim3(FFN_DIM/128, M_TOT/128), 256, 0, stream>>>(
      hbf, w1, nullptr, ffbf, ffn_b1, nullptr, M_TOT, FFN_DIM, D_MODEL);
  // 7. out = x1 + ff @ ffn_w2.T + b2  (4096 x 1024 x 4096) -> fp32, 128x64 depth-2
  gemm_mfma<3,false,64><<<dim3(D_MODEL/64, M_TOT/128), 256, 0, stream>>>(
      ffbf, w2, out, nullptr, ffn_b2, x1, M_TOT, D_MODEL, FFN_DIM);
}